// Round 17
// baseline (156.172 us; speedup 1.0000x reference)
//
#include <hip/hip_runtime.h>
#include <stdint.h>

#define N_NODES 50000
#define N_EDGES 800000
#define F_IN    512
#define F_HID   128
#define F_OUT   3
#define NBLK_SCAN 196     // ceil(50000/256)
#define GEMM_TILES 782    // ceil(50000/64)
#define GEMM_BLOCKS 1564  // 2 split-K blocks per tile
#define HIST_BLOCKS 3125
#define FILL_BLOCKS 3125
#define SCALE_BLOCKS 3125 // 800000 uint4 = 6.4M bf16

typedef __attribute__((ext_vector_type(8))) short short8;
typedef __attribute__((ext_vector_type(4))) float f32x4;

__device__ __forceinline__ unsigned short f2bf(float f) {
  union { float f; unsigned u; } v; v.f = f;
  unsigned r = v.u + 0x7FFFu + ((v.u >> 16) & 1u);
  return (unsigned short)(r >> 16);
}

__device__ __forceinline__ short8 pack8(float4 a, float4 b) {
  short8 r;
  r[0] = (short)f2bf(a.x); r[1] = (short)f2bf(a.y);
  r[2] = (short)f2bf(a.z); r[3] = (short)f2bf(a.w);
  r[4] = (short)f2bf(b.x); r[5] = (short)f2bf(b.y);
  r[6] = (short)f2bf(b.z); r[7] = (short)f2bf(b.w);
  return r;
}

// sum two packed-bf16 pairs in f32, scale by dd, repack
__device__ __forceinline__ unsigned addscale2(unsigned a, unsigned b, float dd) {
  float lo = (__uint_as_float(a << 16) + __uint_as_float(b << 16)) * dd;
  float hi = (__uint_as_float(a & 0xFFFF0000u) + __uint_as_float(b & 0xFFFF0000u)) * dd;
  return (unsigned)f2bf(lo) | ((unsigned)f2bf(hi) << 16);
}

// async 16B global -> LDS (gfx950). LDS dest is wave-uniform base + lane*16;
// global src is per-lane (enables source-side swizzle, m173 pattern).
__device__ __forceinline__ void g2l16(const void* gsrc, void* ldst) {
  __builtin_amdgcn_global_load_lds(
      (const __attribute__((address_space(1))) unsigned int*)gsrc,
      (__attribute__((address_space(3))) unsigned int*)ldst, 16, 0, 0);
}

// ---- prep: W1 -> bf16 transposed [n][k] + zero degree counters --------------
__global__ __launch_bounds__(256) void k_prep(const float* __restrict__ W1,
                                              unsigned short* __restrict__ W1t,
                                              int* __restrict__ count) {
  int idx = blockIdx.x * 256 + threadIdx.x;  // 256 blocks = 65536 threads
  if (idx < N_NODES) count[idx] = 0;
  if (idx < F_IN * F_HID) {
    int k = idx >> 7;    // W1 is [512][128] row-major
    int n = idx & 127;
    W1t[n * F_IN + k] = f2bf(W1[idx]);
  }
}

// ---- merged split-K GEMM1 + histogram ---------------------------------------
// Split-K: 2 blocks per 64-row tile, each covering K/2 = 256 (4 K-tiles).
// Doubles block concurrency (grid 1564, 6.1/CU) at EXACTLY constant A- and
// B-traffic (R14's BM=32 regression doubled B-restage; this doesn't).
// half-0 partial -> h1b buffer, half-1 -> hp1; summed+scaled in k_fill_scale.
__global__ __launch_bounds__(256) void k_gemm1_hist(const float* __restrict__ x,
                                                    const unsigned short* __restrict__ W1t,
                                                    unsigned short* __restrict__ h1b,
                                                    unsigned short* __restrict__ hp1,
                                                    const int* __restrict__ dst,
                                                    int* __restrict__ count) {
  __shared__ float4 AsV[1024];  // 16 KB: 64 rows x 256 B (f32, swizzled)
  __shared__ float4 BsV[1024];  // 16 KB: 128 cols x 128 B (bf16, swizzled)
  const int t = threadIdx.x;

  if (blockIdx.x >= GEMM_BLOCKS) {
    // ---------------- hist body ----------------
    int e = (blockIdx.x - GEMM_BLOCKS) * 256 + t;
    if (e < N_EDGES) atomicAdd(&count[dst[e]], 1);
    return;
  }

  // ---------------- gemm1 body (R11 structure, K-half per block) ------------
  const int tile = blockIdx.x >> 1;
  const int half = blockIdx.x & 1;
  char* AsB = (char*)AsV;
  char* BsB = (char*)BsV;
  const int lane = t & 63;
  const int wid = t >> 6;
  const int lane15 = lane & 15;
  const int kgrp = (lane >> 4) << 3;   // 0,8,16,24
  const int row0 = tile * 64;
  const int wrow = wid << 4;           // wave owns 16 rows

  f32x4 acc[8];
  #pragma unroll
  for (int j = 0; j < 8; ++j) acc[j] = (f32x4)0.0f;

  const int kt0 = half << 2;
  for (int kt = kt0; kt < kt0 + 4; ++kt) {
    const int k0 = kt << 6;
    #pragma unroll
    for (int r = 0; r < 4; ++r) {
      const int i = (wid << 2) + r;          // 0..15, uniform per wave
      const int o = (i << 10) + (lane << 4); // flat LDS byte offset
      {  // A: linear dest; source swizzled so (row, cb) -> cb ^ ((row&7)<<4)
        const int rowA = o >> 8;
        const int cb = (o & 255) ^ ((rowA & 7) << 4);
        int grow = row0 + rowA;
        grow = grow < N_NODES ? grow : N_NODES - 1;  // clamp (store guarded)
        g2l16((const char*)x + (size_t)grow * 2048 + (k0 << 2) + cb,
              AsB + (i << 10));
      }
      {  // B: row = output col n (128 B rows)
        const int nB = o >> 7;
        const int kb = (o & 127) ^ ((nB & 7) << 4);
        g2l16((const char*)W1t + (size_t)nB * 1024 + (k0 << 1) + kb,
              BsB + (i << 10));
      }
    }
    __syncthreads();  // drains global_load_lds
    #pragma unroll
    for (int ks = 0; ks < 2; ++ks) {
      const int kk = (ks << 5) + kgrp;     // k offset in [0,64), multiple of 8
      const int rowL = wrow + lane15;
      const int swA = (rowL & 7) << 4;
      const float4 xa = *reinterpret_cast<const float4*>(AsB + rowL * 256 + (((kk << 2)) ^ swA));
      const float4 xb = *reinterpret_cast<const float4*>(AsB + rowL * 256 + (((kk << 2) + 16) ^ swA));
      const short8 a = pack8(xa, xb);
      #pragma unroll
      for (int nr = 0; nr < 8; ++nr) {
        const int n = (nr << 4) + lane15;
        const short8 b = *reinterpret_cast<const short8*>(BsB + n * 128 + (((kk << 1)) ^ ((n & 7) << 4)));
        acc[nr] = __builtin_amdgcn_mfma_f32_16x16x32_bf16(a, b, acc[nr], 0, 0, 0);
      }
    }
    __syncthreads();  // protect LDS before next tile's staging
  }

  unsigned short* hp = half ? hp1 : h1b;
  const int rgrp = (lane >> 4) << 2;
  const int rowb = row0 + wrow + rgrp;
  #pragma unroll
  for (int nr = 0; nr < 8; ++nr) {
    const int col = (nr << 4) + lane15;
    #pragma unroll
    for (int r = 0; r < 4; ++r) {
      const int row = rowb + r;
      if (row < N_NODES)
        hp[(size_t)row * F_HID + col] = f2bf(acc[nr][r]);  // K-half partial
    }
  }
}

// hierarchical scan, stage 1: per-block exclusive prefix + block sums
__global__ __launch_bounds__(256) void k_scan1(const int* __restrict__ count,
                                               int* __restrict__ local_pre,
                                               int* __restrict__ blocksum) {
  __shared__ int s[256];
  int t = threadIdx.x;
  int i = blockIdx.x * 256 + t;
  int v = (i < N_NODES) ? count[i] : 0;
  s[t] = v;
  __syncthreads();
  #pragma unroll
  for (int off = 1; off < 256; off <<= 1) {
    int u = (t >= off) ? s[t - off] : 0;
    __syncthreads();
    s[t] += u;
    __syncthreads();
  }
  if (i < N_NODES) local_pre[i] = s[t] - v;  // exclusive
  if (t == 255) blocksum[blockIdx.x] = s[255];
}

// stage 2+3 merged: every block redundantly scans the 196 block sums in LDS,
// then finalizes row_ptr / cursor / dinv for its 256 nodes.
__global__ __launch_bounds__(256) void k_scan3(const int* __restrict__ count,
                                               const int* __restrict__ local_pre,
                                               const int* __restrict__ blocksum,
                                               int* __restrict__ row_ptr,
                                               int* __restrict__ cursor,
                                               float* __restrict__ dinv) {
  __shared__ int s[256];
  __shared__ int blockoff;
  int t = threadIdx.x;
  int v = (t < NBLK_SCAN) ? blocksum[t] : 0;
  s[t] = v;
  __syncthreads();
  #pragma unroll
  for (int off = 1; off < 256; off <<= 1) {
    int u = (t >= off) ? s[t - off] : 0;
    __syncthreads();
    s[t] += u;
    __syncthreads();
  }
  if (t == blockIdx.x) blockoff = s[t] - v;  // exclusive prefix of own block
  __syncthreads();
  int i = blockIdx.x * 256 + t;
  if (i < N_NODES) {
    int r = local_pre[i] + blockoff;
    row_ptr[i] = r;
    cursor[i]  = r;
    dinv[i] = rsqrtf((float)(count[i] + 1));
  }
  if (i == 0) row_ptr[N_NODES] = N_EDGES;
}

// ---- merged CSR-fill + split-K reduce + dinv-scale --------------------------
// scale body: h1b[i] = dinv * (h1b[i] + hp1[i]) in f32, in-place on h1b
// (element-wise per thread -> race-free). Hidden under the atomic-bound fill.
__global__ __launch_bounds__(256) void k_fill_scale(const int* __restrict__ src,
                                                    const int* __restrict__ dst,
                                                    int* __restrict__ cursor,
                                                    int* __restrict__ csr_src,
                                                    const float* __restrict__ dinv,
                                                    unsigned short* __restrict__ h1b,
                                                    const unsigned short* __restrict__ hp1) {
  int t = threadIdx.x;
  if (blockIdx.x < FILL_BLOCKS) {
    int e = blockIdx.x * 256 + t;
    if (e < N_EDGES) {
      int d = dst[e];
      int pos = atomicAdd(&cursor[d], 1);
      csr_src[pos] = src[e];
    }
    return;
  }
  // reduce+scale body: 800000 uint4 covering all 50000x128 bf16
  int gid = (blockIdx.x - FILL_BLOCKS) * 256 + t;  // 0..799999
  int row = gid >> 4;
  float dd = dinv[row];
  uint4* p0 = reinterpret_cast<uint4*>(h1b) + gid;
  const uint4* p1 = reinterpret_cast<const uint4*>(hp1) + gid;
  uint4 a = *p0;
  const uint4 b = *p1;
  a.x = addscale2(a.x, b.x, dd);
  a.y = addscale2(a.y, b.y, dd);
  a.z = addscale2(a.z, b.z, dd);
  a.w = addscale2(a.w, b.w, dd);
  *p0 = a;
}

// ---- layer-1 gather + bias + ReLU + GEMM2 fused: wave per node ------------
// R7-proven shape (62.4 us measured): two 32-lane groups, 4 features/lane,
// stride-2 interleave, bf16 rows via uint2, unroll-4, rows pre-scaled by
// dinv[src]. Empirical law (R4+R8+R10, measured thrice): random-row gathers
// must keep 32-lane groups / <=8 B per lane; wider row-spans per instruction
// are request-bound 2.5x slower. t2 stored as padded float4.
__global__ __launch_bounds__(256) void k_agg1_fused(const int* __restrict__ row_ptr,
                                                    const int* __restrict__ csr_src,
                                                    const float* __restrict__ dinv,
                                                    const unsigned short* __restrict__ h1b,
                                                    const float* __restrict__ b1,
                                                    const float* __restrict__ W2,
                                                    float* __restrict__ t2p) {
  int t = threadIdx.x;
  int lane = t & 63;
  int node = blockIdx.x * 4 + (t >> 6);  // 50000 = 12500*4, no tail
  int g = lane >> 5;
  int fl = (lane & 31) << 2;
  float dd = dinv[node];
  f32x4 acc = (f32x4)0.0f;
  if (g == 0) {  // self loop contributes h1'[node]
    const uint2 sv = *reinterpret_cast<const uint2*>(h1b + (size_t)node * F_HID + fl);
    acc[0] = __uint_as_float(sv.x << 16);
    acc[1] = __uint_as_float(sv.x & 0xFFFF0000u);
    acc[2] = __uint_as_float(sv.y << 16);
    acc[3] = __uint_as_float(sv.y & 0xFFFF0000u);
  }
  int start = row_ptr[node], end = row_ptr[node + 1];
  int i = start + g;
  // unroll-4: edges i, i+2, i+4, i+6 -> 4 rows in flight per group
  for (; i + 6 < end; i += 8) {
    int s0 = csr_src[i];
    int s1 = csr_src[i + 2];
    int s2 = csr_src[i + 4];
    int s3 = csr_src[i + 6];
    const uint2 v0 = *reinterpret_cast<const uint2*>(h1b + (size_t)s0 * F_HID + fl);
    const uint2 v1 = *reinterpret_cast<const uint2*>(h1b + (size_t)s1 * F_HID + fl);
    const uint2 v2 = *reinterpret_cast<const uint2*>(h1b + (size_t)s2 * F_HID + fl);
    const uint2 v3 = *reinterpret_cast<const uint2*>(h1b + (size_t)s3 * F_HID + fl);
    acc[0] += __uint_as_float(v0.x << 16);
    acc[1] += __uint_as_float(v0.x & 0xFFFF0000u);
    acc[2] += __uint_as_float(v0.y << 16);
    acc[3] += __uint_as_float(v0.y & 0xFFFF0000u);
    acc[0] += __uint_as_float(v1.x << 16);
    acc[1] += __uint_as_float(v1.x & 0xFFFF0000u);
    acc[2] += __uint_as_float(v1.y << 16);
    acc[3] += __uint_as_float(v1.y & 0xFFFF0000u);
    acc[0] += __uint_as_float(v2.x << 16);
    acc[1] += __uint_as_float(v2.x & 0xFFFF0000u);
    acc[2] += __uint_as_float(v2.y << 16);
    acc[3] += __uint_as_float(v2.y & 0xFFFF0000u);
    acc[0] += __uint_as_float(v3.x << 16);
    acc[1] += __uint_as_float(v3.x & 0xFFFF0000u);
    acc[2] += __uint_as_float(v3.y << 16);
    acc[3] += __uint_as_float(v3.y & 0xFFFF0000u);
  }
  for (; i < end; i += 2) {
    int s = csr_src[i];
    const uint2 v = *reinterpret_cast<const uint2*>(h1b + (size_t)s * F_HID + fl);
    acc[0] += __uint_as_float(v.x << 16);
    acc[1] += __uint_as_float(v.x & 0xFFFF0000u);
    acc[2] += __uint_as_float(v.y << 16);
    acc[3] += __uint_as_float(v.y & 0xFFFF0000u);
  }
  // combine the two edge-groups: lanes 0-31 += lanes 32-63
  #pragma unroll
  for (int j = 0; j < 4; ++j) {
    float o = __shfl(acc[j], (lane & 31) + 32);
    acc[j] += o;
  }
  // features = b1 + dd * acc; relu
  const float4 bb = *reinterpret_cast<const float4*>(b1 + fl);
  float v0 = fmaxf(fmaf(dd, acc[0], bb.x), 0.0f);
  float v1 = fmaxf(fmaf(dd, acc[1], bb.y), 0.0f);
  float v2 = fmaxf(fmaf(dd, acc[2], bb.z), 0.0f);
  float v3 = fmaxf(fmaf(dd, acc[3], bb.w), 0.0f);
  // 128->3 dot products; W2 is [128][3] row-major; store t2' = dinv[node]*t2
  const float* w2r = W2 + fl * 3;
  float pr[3];
  #pragma unroll
  for (int c = 0; c < 3; ++c) {
    float p = v0 * w2r[c] + v1 * w2r[3 + c] + v2 * w2r[6 + c] + v3 * w2r[9 + c];
    p += __shfl_down(p, 16);
    p += __shfl_down(p, 8);
    p += __shfl_down(p, 4);
    p += __shfl_down(p, 2);
    p += __shfl_down(p, 1);
    pr[c] = p;
  }
  if (lane == 0) {
    float4 o;
    o.x = dd * pr[0]; o.y = dd * pr[1]; o.z = dd * pr[2]; o.w = 0.0f;
    *reinterpret_cast<float4*>(t2p + (size_t)node * 4) = o;
  }
}

// ---- layer-2 gather: 16 lanes per node; t2p rows padded to 16 B -> one
// dwordx4 per edge.
__global__ __launch_bounds__(256) void k_agg2(const int* __restrict__ row_ptr,
                                              const int* __restrict__ csr_src,
                                              const float* __restrict__ dinv,
                                              const float* __restrict__ t2p,
                                              const float* __restrict__ b2,
                                              float* __restrict__ out) {
  int t = threadIdx.x;
  int node = blockIdx.x * 16 + (t >> 4);
  if (node >= N_NODES) return;
  int sl = t & 15;
  float a0 = 0.f, a1 = 0.f, a2 = 0.f;
  int start = row_ptr[node], end = row_ptr[node + 1];
  for (int i = start + sl; i < end; i += 16) {
    int s = csr_src[i];
    const float4 v = *reinterpret_cast<const float4*>(t2p + (size_t)s * 4);
    a0 += v.x; a1 += v.y; a2 += v.z;
  }
  #pragma unroll
  for (int off = 8; off > 0; off >>= 1) {
    a0 += __shfl_down(a0, off);
    a1 += __shfl_down(a1, off);
    a2 += __shfl_down(a2, off);
  }
  if (sl == 0) {
    float dd = dinv[node];
    const float4 sv = *reinterpret_cast<const float4*>(t2p + (size_t)node * 4);
    out[node * 3 + 0] = fmaf(dd, sv.x + a0, b2[0]);
    out[node * 3 + 1] = fmaf(dd, sv.y + a1, b2[1]);
    out[node * 3 + 2] = fmaf(dd, sv.z + a2, b2[2]);
  }
}

extern "C" void kernel_launch(void* const* d_in, const int* in_sizes, int n_in,
                              void* d_out, int out_size, void* d_ws, size_t ws_size,
                              hipStream_t stream) {
  const float* x  = (const float*)d_in[0];
  const int*   ei = (const int*)d_in[1];
  const float* W1 = (const float*)d_in[2];
  const float* b1 = (const float*)d_in[3];
  const float* W2 = (const float*)d_in[4];
  const float* b2 = (const float*)d_in[5];
  const int* src = ei;
  const int* dst = ei + N_EDGES;
  float* out = (float*)d_out;

  char* ws = (char*)d_ws;
  // ws layout (16B aligned), total ~30.7 MB:
  float*          dinv    = (float*)(ws + 0);          // 200000 B
  int*            count   = (int*)  (ws + 200704);     // 200000 B
  int*            cursor  = (int*)  (ws + 401408);     // 200000 B
  int*            row_ptr = (int*)  (ws + 602112);     // 200004 B
  int*            csr_src = (int*)  (ws + 802816);     // 3200000 B
  unsigned short* W1t     = (unsigned short*)(ws + 4002816);  // 131072 B
  float*          t2p     = (float*)(ws + 4133888);    // 800000 B (padded 4/node)
  int*            local_pre = (int*)(ws + 4934656);    // 200000 B
  int*            blocksum  = (int*)(ws + 5134656);    // 784 B
  unsigned short* h1b     = (unsigned short*)(ws + 5135872);   // 12800000 B (K-half-0 partial, then final)
  unsigned short* hp1     = (unsigned short*)(ws + 17935872);  // 12800000 B (K-half-1 partial)

  k_prep      <<<256, 256, 0, stream>>>(W1, W1t, count);
  k_gemm1_hist<<<GEMM_BLOCKS + HIST_BLOCKS, 256, 0, stream>>>(x, W1t, h1b, hp1, dst, count);
  k_scan1     <<<NBLK_SCAN, 256, 0, stream>>>(count, local_pre, blocksum);
  k_scan3     <<<NBLK_SCAN, 256, 0, stream>>>(count, local_pre, blocksum, row_ptr, cursor, dinv);
  k_fill_scale<<<FILL_BLOCKS + SCALE_BLOCKS, 256, 0, stream>>>(src, dst, cursor, csr_src, dinv, h1b, hp1);
  k_agg1_fused<<<N_NODES / 4, 256, 0, stream>>>(row_ptr, csr_src, dinv, h1b, b1, W2, t2p);
  k_agg2      <<<(N_NODES + 15) / 16, 256, 0, stream>>>(row_ptr, csr_src, dinv, t2p, b2, out);
}

// Round 18
// 119.028 us; speedup vs baseline: 1.3121x; 1.3121x over previous
//
#include <hip/hip_runtime.h>
#include <stdint.h>

#define N_NODES 50000
#define N_EDGES 800000
#define F_IN    512
#define F_HID   128
#define F_OUT   3
#define NBLK_SCAN 196    // ceil(50000/256)
#define GEMM_BLOCKS 782  // ceil(50000/64)
#define HIST_BLOCKS 3125
#define FILL_BLOCKS 3125
#define SCALE_BLOCKS 3125  // 800000 uint4 = 6.4M bf16

typedef __attribute__((ext_vector_type(8))) short short8;
typedef __attribute__((ext_vector_type(4))) float f32x4;

__device__ __forceinline__ unsigned short f2bf(float f) {
  union { float f; unsigned u; } v; v.f = f;
  unsigned r = v.u + 0x7FFFu + ((v.u >> 16) & 1u);
  return (unsigned short)(r >> 16);
}

__device__ __forceinline__ short8 pack8(float4 a, float4 b) {
  short8 r;
  r[0] = (short)f2bf(a.x); r[1] = (short)f2bf(a.y);
  r[2] = (short)f2bf(a.z); r[3] = (short)f2bf(a.w);
  r[4] = (short)f2bf(b.x); r[5] = (short)f2bf(b.y);
  r[6] = (short)f2bf(b.z); r[7] = (short)f2bf(b.w);
  return r;
}

// scale two packed bf16 by dd, repack
__device__ __forceinline__ unsigned scale2(unsigned u, float dd) {
  float lo = __uint_as_float(u << 16) * dd;
  float hi = __uint_as_float(u & 0xFFFF0000u) * dd;
  return (unsigned)f2bf(lo) | ((unsigned)f2bf(hi) << 16);
}

// async 16B global -> LDS (gfx950). LDS dest is wave-uniform base + lane*16;
// global src is per-lane (enables source-side swizzle, m173 pattern).
__device__ __forceinline__ void g2l16(const void* gsrc, void* ldst) {
  __builtin_amdgcn_global_load_lds(
      (const __attribute__((address_space(1))) unsigned int*)gsrc,
      (__attribute__((address_space(3))) unsigned int*)ldst, 16, 0, 0);
}

// ---- prep: W1 -> bf16 transposed [n][k] + zero degree counters --------------
__global__ __launch_bounds__(256) void k_prep(const float* __restrict__ W1,
                                              unsigned short* __restrict__ W1t,
                                              int* __restrict__ count) {
  int idx = blockIdx.x * 256 + threadIdx.x;  // 256 blocks = 65536 threads
  if (idx < N_NODES) count[idx] = 0;
  if (idx < F_IN * F_HID) {
    int k = idx >> 7;    // W1 is [512][128] row-major
    int n = idx & 127;
    W1t[n * F_IN + k] = f2bf(W1[idx]);
  }
}

// ---- merged GEMM1(raw) + histogram ------------------------------------------
// gemm1 depends only on W1t+x and overlaps the 800k-atomic histogram.
// NEW: hist stores the atomicAdd return as rank[e] (each edge's unique slot
// within its dst node) -> the later CSR fill needs NO atomics.
__global__ __launch_bounds__(256) void k_gemm1_hist(const float* __restrict__ x,
                                                    const unsigned short* __restrict__ W1t,
                                                    unsigned short* __restrict__ h1b,
                                                    const int* __restrict__ dst,
                                                    int* __restrict__ count,
                                                    int* __restrict__ rank) {
  __shared__ float4 AsV[1024];  // 16 KB: 64 rows x 256 B (f32, swizzled)
  __shared__ float4 BsV[1024];  // 16 KB: 128 cols x 128 B (bf16, swizzled)
  const int t = threadIdx.x;

  if (blockIdx.x >= GEMM_BLOCKS) {
    // ---------------- hist body ----------------
    int e = (blockIdx.x - GEMM_BLOCKS) * 256 + t;
    if (e < N_EDGES) rank[e] = atomicAdd(&count[dst[e]], 1);
    return;
  }

  // ---------------- gemm1 body (R11 structure, no dinv) ----------------
  char* AsB = (char*)AsV;
  char* BsB = (char*)BsV;
  const int lane = t & 63;
  const int wid = t >> 6;
  const int lane15 = lane & 15;
  const int kgrp = (lane >> 4) << 3;   // 0,8,16,24
  const int row0 = blockIdx.x * 64;
  const int wrow = wid << 4;           // wave owns 16 rows

  f32x4 acc[8];
  #pragma unroll
  for (int j = 0; j < 8; ++j) acc[j] = (f32x4)0.0f;

  for (int kt = 0; kt < 8; ++kt) {
    const int k0 = kt << 6;
    #pragma unroll
    for (int r = 0; r < 4; ++r) {
      const int i = (wid << 2) + r;          // 0..15, uniform per wave
      const int o = (i << 10) + (lane << 4); // flat LDS byte offset
      {  // A: linear dest; source swizzled so (row, cb) -> cb ^ ((row&7)<<4)
        const int rowA = o >> 8;
        const int cb = (o & 255) ^ ((rowA & 7) << 4);
        int grow = row0 + rowA;
        grow = grow < N_NODES ? grow : N_NODES - 1;  // clamp (store guarded)
        g2l16((const char*)x + (size_t)grow * 2048 + (k0 << 2) + cb,
              AsB + (i << 10));
      }
      {  // B: row = output col n (128 B rows)
        const int nB = o >> 7;
        const int kb = (o & 127) ^ ((nB & 7) << 4);
        g2l16((const char*)W1t + (size_t)nB * 1024 + (k0 << 1) + kb,
              BsB + (i << 10));
      }
    }
    __syncthreads();  // drains global_load_lds
    #pragma unroll
    for (int ks = 0; ks < 2; ++ks) {
      const int kk = (ks << 5) + kgrp;     // k offset in [0,64), multiple of 8
      const int rowL = wrow + lane15;
      const int swA = (rowL & 7) << 4;
      const float4 xa = *reinterpret_cast<const float4*>(AsB + rowL * 256 + (((kk << 2)) ^ swA));
      const float4 xb = *reinterpret_cast<const float4*>(AsB + rowL * 256 + (((kk << 2) + 16) ^ swA));
      const short8 a = pack8(xa, xb);
      #pragma unroll
      for (int nr = 0; nr < 8; ++nr) {
        const int n = (nr << 4) + lane15;
        const short8 b = *reinterpret_cast<const short8*>(BsB + n * 128 + (((kk << 1)) ^ ((n & 7) << 4)));
        acc[nr] = __builtin_amdgcn_mfma_f32_16x16x32_bf16(a, b, acc[nr], 0, 0, 0);
      }
    }
    __syncthreads();  // protect LDS before next tile's staging
  }

  const int rgrp = (lane >> 4) << 2;
  const int rowb = row0 + wrow + rgrp;
  #pragma unroll
  for (int nr = 0; nr < 8; ++nr) {
    const int col = (nr << 4) + lane15;
    #pragma unroll
    for (int r = 0; r < 4; ++r) {
      const int row = rowb + r;
      if (row < N_NODES)
        h1b[(size_t)row * F_HID + col] = f2bf(acc[nr][r]);  // raw, unscaled
    }
  }
}

// hierarchical scan, stage 1: per-block exclusive prefix + block sums
__global__ __launch_bounds__(256) void k_scan1(const int* __restrict__ count,
                                               int* __restrict__ local_pre,
                                               int* __restrict__ blocksum) {
  __shared__ int s[256];
  int t = threadIdx.x;
  int i = blockIdx.x * 256 + t;
  int v = (i < N_NODES) ? count[i] : 0;
  s[t] = v;
  __syncthreads();
  #pragma unroll
  for (int off = 1; off < 256; off <<= 1) {
    int u = (t >= off) ? s[t - off] : 0;
    __syncthreads();
    s[t] += u;
    __syncthreads();
  }
  if (i < N_NODES) local_pre[i] = s[t] - v;  // exclusive
  if (t == 255) blocksum[blockIdx.x] = s[255];
}

// stage 2+3 merged: every block redundantly scans the 196 block sums in LDS,
// then finalizes row_ptr / dinv for its 256 nodes (no cursor needed anymore).
__global__ __launch_bounds__(256) void k_scan3(const int* __restrict__ count,
                                               const int* __restrict__ local_pre,
                                               const int* __restrict__ blocksum,
                                               int* __restrict__ row_ptr,
                                               float* __restrict__ dinv) {
  __shared__ int s[256];
  __shared__ int blockoff;
  int t = threadIdx.x;
  int v = (t < NBLK_SCAN) ? blocksum[t] : 0;
  s[t] = v;
  __syncthreads();
  #pragma unroll
  for (int off = 1; off < 256; off <<= 1) {
    int u = (t >= off) ? s[t - off] : 0;
    __syncthreads();
    s[t] += u;
    __syncthreads();
  }
  if (t == blockIdx.x) blockoff = s[t] - v;  // exclusive prefix of own block
  __syncthreads();
  int i = blockIdx.x * 256 + t;
  if (i < N_NODES) {
    row_ptr[i] = local_pre[i] + blockoff;
    dinv[i] = rsqrtf((float)(count[i] + 1));
  }
  if (i == 0) row_ptr[N_NODES] = N_EDGES;
}

// ---- merged atomic-free CSR-fill + h1 dinv-scale ----------------------------
// fill: pos = row_ptr[dst[e]] + rank[e] (rank captured during hist) -> plain
// gather+scatter, no atomic rmw. scale: streaming 12.8 MB rmw, hidden.
__global__ __launch_bounds__(256) void k_fill_scale(const int* __restrict__ src,
                                                    const int* __restrict__ dst,
                                                    const int* __restrict__ row_ptr,
                                                    const int* __restrict__ rank,
                                                    int* __restrict__ csr_src,
                                                    const float* __restrict__ dinv,
                                                    unsigned short* __restrict__ h1b) {
  int t = threadIdx.x;
  if (blockIdx.x < FILL_BLOCKS) {
    int e = blockIdx.x * 256 + t;
    if (e < N_EDGES) {
      int pos = row_ptr[dst[e]] + rank[e];
      csr_src[pos] = src[e];
    }
    return;
  }
  // scale body: 800000 uint4 covering all 50000x128 bf16 (16 uint4 per row)
  int gid = (blockIdx.x - FILL_BLOCKS) * 256 + t;  // 0..799999
  int row = gid >> 4;
  float dd = dinv[row];
  uint4* p = reinterpret_cast<uint4*>(h1b) + gid;
  uint4 v = *p;
  v.x = scale2(v.x, dd);
  v.y = scale2(v.y, dd);
  v.z = scale2(v.z, dd);
  v.w = scale2(v.w, dd);
  *p = v;
}

// ---- layer-1 gather + bias + ReLU + GEMM2 fused: wave per node ------------
// R7-proven shape (62.4 us measured): two 32-lane groups, 4 features/lane,
// stride-2 interleave, bf16 rows via uint2, unroll-4, rows pre-scaled by
// dinv[src]. Empirical law (R4+R8+R10, measured thrice): random-row gathers
// must keep 32-lane groups / <=8 B per lane; wider row-spans per instruction
// are request-bound 2.5x slower. t2 stored as padded float4.
__global__ __launch_bounds__(256) void k_agg1_fused(const int* __restrict__ row_ptr,
                                                    const int* __restrict__ csr_src,
                                                    const float* __restrict__ dinv,
                                                    const unsigned short* __restrict__ h1b,
                                                    const float* __restrict__ b1,
                                                    const float* __restrict__ W2,
                                                    float* __restrict__ t2p) {
  int t = threadIdx.x;
  int lane = t & 63;
  int node = blockIdx.x * 4 + (t >> 6);  // 50000 = 12500*4, no tail
  int g = lane >> 5;
  int fl = (lane & 31) << 2;
  float dd = dinv[node];
  f32x4 acc = (f32x4)0.0f;
  if (g == 0) {  // self loop contributes h1'[node]
    const uint2 sv = *reinterpret_cast<const uint2*>(h1b + (size_t)node * F_HID + fl);
    acc[0] = __uint_as_float(sv.x << 16);
    acc[1] = __uint_as_float(sv.x & 0xFFFF0000u);
    acc[2] = __uint_as_float(sv.y << 16);
    acc[3] = __uint_as_float(sv.y & 0xFFFF0000u);
  }
  int start = row_ptr[node], end = row_ptr[node + 1];
  int i = start + g;
  // unroll-4: edges i, i+2, i+4, i+6 -> 4 rows in flight per group
  for (; i + 6 < end; i += 8) {
    int s0 = csr_src[i];
    int s1 = csr_src[i + 2];
    int s2 = csr_src[i + 4];
    int s3 = csr_src[i + 6];
    const uint2 v0 = *reinterpret_cast<const uint2*>(h1b + (size_t)s0 * F_HID + fl);
    const uint2 v1 = *reinterpret_cast<const uint2*>(h1b + (size_t)s1 * F_HID + fl);
    const uint2 v2 = *reinterpret_cast<const uint2*>(h1b + (size_t)s2 * F_HID + fl);
    const uint2 v3 = *reinterpret_cast<const uint2*>(h1b + (size_t)s3 * F_HID + fl);
    acc[0] += __uint_as_float(v0.x << 16);
    acc[1] += __uint_as_float(v0.x & 0xFFFF0000u);
    acc[2] += __uint_as_float(v0.y << 16);
    acc[3] += __uint_as_float(v0.y & 0xFFFF0000u);
    acc[0] += __uint_as_float(v1.x << 16);
    acc[1] += __uint_as_float(v1.x & 0xFFFF0000u);
    acc[2] += __uint_as_float(v1.y << 16);
    acc[3] += __uint_as_float(v1.y & 0xFFFF0000u);
    acc[0] += __uint_as_float(v2.x << 16);
    acc[1] += __uint_as_float(v2.x & 0xFFFF0000u);
    acc[2] += __uint_as_float(v2.y << 16);
    acc[3] += __uint_as_float(v2.y & 0xFFFF0000u);
    acc[0] += __uint_as_float(v3.x << 16);
    acc[1] += __uint_as_float(v3.x & 0xFFFF0000u);
    acc[2] += __uint_as_float(v3.y << 16);
    acc[3] += __uint_as_float(v3.y & 0xFFFF0000u);
  }
  for (; i < end; i += 2) {
    int s = csr_src[i];
    const uint2 v = *reinterpret_cast<const uint2*>(h1b + (size_t)s * F_HID + fl);
    acc[0] += __uint_as_float(v.x << 16);
    acc[1] += __uint_as_float(v.x & 0xFFFF0000u);
    acc[2] += __uint_as_float(v.y << 16);
    acc[3] += __uint_as_float(v.y & 0xFFFF0000u);
  }
  // combine the two edge-groups: lanes 0-31 += lanes 32-63
  #pragma unroll
  for (int j = 0; j < 4; ++j) {
    float o = __shfl(acc[j], (lane & 31) + 32);
    acc[j] += o;
  }
  // features = b1 + dd * acc; relu
  const float4 bb = *reinterpret_cast<const float4*>(b1 + fl);
  float v0 = fmaxf(fmaf(dd, acc[0], bb.x), 0.0f);
  float v1 = fmaxf(fmaf(dd, acc[1], bb.y), 0.0f);
  float v2 = fmaxf(fmaf(dd, acc[2], bb.z), 0.0f);
  float v3 = fmaxf(fmaf(dd, acc[3], bb.w), 0.0f);
  // 128->3 dot products; W2 is [128][3] row-major; store t2' = dinv[node]*t2
  const float* w2r = W2 + fl * 3;
  float pr[3];
  #pragma unroll
  for (int c = 0; c < 3; ++c) {
    float p = v0 * w2r[c] + v1 * w2r[3 + c] + v2 * w2r[6 + c] + v3 * w2r[9 + c];
    p += __shfl_down(p, 16);
    p += __shfl_down(p, 8);
    p += __shfl_down(p, 4);
    p += __shfl_down(p, 2);
    p += __shfl_down(p, 1);
    pr[c] = p;
  }
  if (lane == 0) {
    float4 o;
    o.x = dd * pr[0]; o.y = dd * pr[1]; o.z = dd * pr[2]; o.w = 0.0f;
    *reinterpret_cast<float4*>(t2p + (size_t)node * 4) = o;
  }
}

// ---- layer-2 gather: 16 lanes per node; t2p rows padded to 16 B -> one
// dwordx4 per edge.
__global__ __launch_bounds__(256) void k_agg2(const int* __restrict__ row_ptr,
                                              const int* __restrict__ csr_src,
                                              const float* __restrict__ dinv,
                                              const float* __restrict__ t2p,
                                              const float* __restrict__ b2,
                                              float* __restrict__ out) {
  int t = threadIdx.x;
  int node = blockIdx.x * 16 + (t >> 4);
  if (node >= N_NODES) return;
  int sl = t & 15;
  float a0 = 0.f, a1 = 0.f, a2 = 0.f;
  int start = row_ptr[node], end = row_ptr[node + 1];
  for (int i = start + sl; i < end; i += 16) {
    int s = csr_src[i];
    const float4 v = *reinterpret_cast<const float4*>(t2p + (size_t)s * 4);
    a0 += v.x; a1 += v.y; a2 += v.z;
  }
  #pragma unroll
  for (int off = 8; off > 0; off >>= 1) {
    a0 += __shfl_down(a0, off);
    a1 += __shfl_down(a1, off);
    a2 += __shfl_down(a2, off);
  }
  if (sl == 0) {
    float dd = dinv[node];
    const float4 sv = *reinterpret_cast<const float4*>(t2p + (size_t)node * 4);
    out[node * 3 + 0] = fmaf(dd, sv.x + a0, b2[0]);
    out[node * 3 + 1] = fmaf(dd, sv.y + a1, b2[1]);
    out[node * 3 + 2] = fmaf(dd, sv.z + a2, b2[2]);
  }
}

extern "C" void kernel_launch(void* const* d_in, const int* in_sizes, int n_in,
                              void* d_out, int out_size, void* d_ws, size_t ws_size,
                              hipStream_t stream) {
  const float* x  = (const float*)d_in[0];
  const int*   ei = (const int*)d_in[1];
  const float* W1 = (const float*)d_in[2];
  const float* b1 = (const float*)d_in[3];
  const float* W2 = (const float*)d_in[4];
  const float* b2 = (const float*)d_in[5];
  const int* src = ei;
  const int* dst = ei + N_EDGES;
  float* out = (float*)d_out;

  char* ws = (char*)d_ws;
  // ws layout (16B aligned), total ~21.2 MB:
  float*          dinv    = (float*)(ws + 0);          // 200000 B
  int*            count   = (int*)  (ws + 200704);     // 200000 B
  int*            rank    = (int*)  (ws + 401408);     // 3200000 B
  int*            row_ptr = (int*)  (ws + 3601408);    // 200004 B
  int*            csr_src = (int*)  (ws + 3801600);    // 3200000 B
  unsigned short* W1t     = (unsigned short*)(ws + 7001600);  // 131072 B
  float*          t2p     = (float*)(ws + 7132672);    // 800000 B (padded 4/node)
  int*            local_pre = (int*)(ws + 7933440);    // 200000 B
  int*            blocksum  = (int*)(ws + 8133440);    // 784 B
  unsigned short* h1b     = (unsigned short*)(ws + 8134656);  // 12800000 B

  k_prep      <<<256, 256, 0, stream>>>(W1, W1t, count);
  k_gemm1_hist<<<GEMM_BLOCKS + HIST_BLOCKS, 256, 0, stream>>>(x, W1t, h1b, dst, count, rank);
  k_scan1     <<<NBLK_SCAN, 256, 0, stream>>>(count, local_pre, blocksum);
  k_scan3     <<<NBLK_SCAN, 256, 0, stream>>>(count, local_pre, blocksum, row_ptr, dinv);
  k_fill_scale<<<FILL_BLOCKS + SCALE_BLOCKS, 256, 0, stream>>>(src, dst, row_ptr, rank, csr_src, dinv, h1b);
  k_agg1_fused<<<N_NODES / 4, 256, 0, stream>>>(row_ptr, csr_src, dinv, h1b, b1, W2, t2p);
  k_agg2      <<<(N_NODES + 15) / 16, 256, 0, stream>>>(row_ptr, csr_src, dinv, t2p, b2, out);
}